// Round 2
// 288.362 us; speedup vs baseline: 1.0439x; 1.0439x over previous
//
#include <hip/hip_runtime.h>

#define RPB 256  // threads per block = rows per block (4 waves x 64 rows)

// Native clang vector type: __builtin_nontemporal_* requires a vector of
// scalar types, not HIP's struct float4. Same layout/alignment (16B).
typedef float fvec4 __attribute__((ext_vector_type(4)));

// Wave-private staging: each 64-lane wave owns 64 rows and a private LDS
// slice (64*22 floats = 5632 B). DS ops within a wave complete in order, so
// no __syncthreads() is needed anywhere -- each wave streams independently.
// __builtin_amdgcn_wave_barrier() is a zero-cost compile-time fence that
// stops the scheduler reordering the cross-lane LDS phases.
__global__ __launch_bounds__(RPB) void se3_ham_kernel(
    const float* __restrict__ in, float* __restrict__ out, int n_rows) {
    __shared__ float s[RPB * 22];

    const int wave = threadIdx.x >> 6;
    const int lane = threadIdx.x & 63;
    const int row0 = blockIdx.x * RPB + (wave << 6);  // this wave's first row
    if (row0 >= n_rows) return;  // safe: no block-level barriers below
    int count = n_rows - row0;
    if (count > 64) count = 64;
    const int nf  = count * 22;   // floats this wave stages
    const int nf4 = nf >> 2;

    float* const sw = s + wave * (64 * 22);
    fvec4* const s4 = (fvec4*)sw;

    // ---- phase A: wave-private coalesced load, global -> LDS (nontemporal) ----
    const float* gin  = in + (size_t)row0 * 22;
    const fvec4* gin4 = (const fvec4*)gin;
    for (int i = lane; i < nf4; i += 64)
        s4[i] = __builtin_nontemporal_load(&gin4[i]);
    for (int i = (nf4 << 2) + lane; i < nf; i += 64)
        sw[i] = __builtin_nontemporal_load(&gin[i]);
    __builtin_amdgcn_wave_barrier();

    // ---- phase B: per-row physics, in place in this lane's LDS row ----
    if (lane < count) {
        float* p = &sw[lane * 22];
        const float R00=p[3],  R01=p[4],  R02=p[5];
        const float R10=p[6],  R11=p[7],  R12=p[8];
        const float R20=p[9],  R21=p[10], R22=p[11];
        const float qv0=p[12], qv1=p[13], qv2=p[14];
        const float qw0=p[15], qw1=p[16], qw2=p[17];
        const float u0 =p[18], u1 =p[19], u2 =p[20], u3=p[21];

        // constants (double-derived, matching numpy's float32-cast values)
        const float M1d   = (float)(1.0 / (1.0 / 0.027));   // inv(M*I) diag = 0.027
        const float Minv  = (float)(1.0 / 0.027);           // M1_INV diag
        const float Jx    = (float)2.3951e-05;
        const float Jz    = (float)3.2347e-05;
        const float Jxinv = (float)(1.0 / 2.3951e-05);
        const float Jzinv = (float)(1.0 / 3.2347e-05);
        const float MG    = (float)(0.027 * 9.81);

        // momenta
        const float pv0 = M1d * qv0, pv1 = M1d * qv1, pv2 = M1d * qv2;
        const float pw0 = Jx * qw0,  pw1 = Jx * qw1,  pw2 = Jz * qw2;
        // gradients
        const float hv0 = Minv * pv0, hv1 = Minv * pv1, hv2 = Minv * pv2;
        const float hw0 = Jxinv * pw0, hw1 = Jxinv * pw1, hw2 = Jzinv * pw2;

        // dpv = cross(pv, hw) - MG*R_row2 + (0,0,u0)
        const float dpv0 = (pv1*hw2 - pv2*hw1) - MG*R20;
        const float dpv1 = (pv2*hw0 - pv0*hw2) - MG*R21;
        const float dpv2 = (pv0*hw1 - pv1*hw0) - MG*R22 + u0;
        // dpw = cross(pw, hw) + cross(pv, hv) + (u1,u2,u3)
        const float dpw0 = (pw1*hw2 - pw2*hw1) + (pv1*hv2 - pv2*hv1) + u1;
        const float dpw1 = (pw2*hw0 - pw0*hw2) + (pv2*hv0 - pv0*hv2) + u2;
        const float dpw2 = (pw0*hw1 - pw1*hw0) + (pv0*hv1 - pv1*hv0) + u3;

        // dx = R * dHdpv
        p[0] = R00*hv0 + R01*hv1 + R02*hv2;
        p[1] = R10*hv0 + R11*hv1 + R12*hv2;
        p[2] = R20*hv0 + R21*hv1 + R22*hv2;

        // dR rows: cross(R_row_i, hw)
        p[3]  = R01*hw2 - R02*hw1;  p[4]  = R02*hw0 - R00*hw2;  p[5]  = R00*hw1 - R01*hw0;
        p[6]  = R11*hw2 - R12*hw1;  p[7]  = R12*hw0 - R10*hw2;  p[8]  = R10*hw1 - R11*hw0;
        p[9]  = R21*hw2 - R22*hw1;  p[10] = R22*hw0 - R20*hw2;  p[11] = R20*hw1 - R21*hw0;

        // dv = Minv * dpv ; dw = Jinv * dpw
        p[12] = Minv * dpv0;  p[13] = Minv * dpv1;  p[14] = Minv * dpv2;
        p[15] = Jxinv * dpw0; p[16] = Jxinv * dpw1; p[17] = Jzinv * dpw2;

        // trailing zeros
        p[18] = 0.0f; p[19] = 0.0f; p[20] = 0.0f; p[21] = 0.0f;
    }
    __builtin_amdgcn_wave_barrier();

    // ---- phase C: wave-private coalesced store, LDS -> global (nontemporal) ----
    float* gout  = out + (size_t)row0 * 22;
    fvec4* gout4 = (fvec4*)gout;
    for (int i = lane; i < nf4; i += 64)
        __builtin_nontemporal_store(s4[i], &gout4[i]);
    for (int i = (nf4 << 2) + lane; i < nf; i += 64)
        gout[i] = sw[i];
}

extern "C" void kernel_launch(void* const* d_in, const int* in_sizes, int n_in,
                              void* d_out, int out_size, void* d_ws, size_t ws_size,
                              hipStream_t stream) {
    // d_in[0] = t (unused scalar), d_in[1] = input [BS, 22] float32
    const float* x = (const float*)d_in[1];
    float* y = (float*)d_out;
    const int n_rows = in_sizes[1] / 22;
    const int blocks = (n_rows + RPB - 1) / RPB;
    se3_ham_kernel<<<blocks, RPB, 0, stream>>>(x, y, n_rows);
}